// Round 14
// baseline (263.832 us; speedup 1.0000x reference)
//
#include <hip/hip_runtime.h>

// WindowAttention: B=8, C=128, H=W=256, ws=8, heads=4, d=32, n=64 tokens/window
// r14: 8192 blocks x 128 thr (2 waves). Wave wv handles heads {2wv, 2wv+1}
// SEQUENTIALLY (#pragma unroll 1) with no sync between the staging barrier and
// the Ot barrier -> 5 independent blocks/CU (LDS 32K) = 5 desynchronized
// phase-streams (vs r13's 2.5 barrier-locked). Same math as r13:
// x32 MFMA projections (swapped-operand), x16 MFMA attention (k-mapping ==
// x32 C/D layout -> Q/K/V/P in registers), packed Ot b64 stores, setprio,
// exp2-domain softmax (SCALE*log2e folded into Wq).
// LDS 32K: [0,16K) Xt[64][128]bf16 swz(tok&15)<<4; [16K,32K) Ot. 2 barriers.

#define HH    256
#define WWID  256
#define SCALE 0.17677669529663687f
#define LOG2E 1.44269504088896340736f

typedef float  f32x4  __attribute__((ext_vector_type(4)));
typedef __bf16 bf16x8 __attribute__((ext_vector_type(8)));
typedef __bf16 bf16x4 __attribute__((ext_vector_type(4)));
typedef __bf16 bf16x2 __attribute__((ext_vector_type(2)));
typedef short  s16x4  __attribute__((ext_vector_type(4)));

#define OT_BASE 16384

__device__ __forceinline__ s16x4 pack4(f32x4 v) {
  bf16x4 b = {(__bf16)v[0], (__bf16)v[1], (__bf16)v[2], (__bf16)v[3]};
  return __builtin_bit_cast(s16x4, b);
}

#if __has_builtin(__builtin_amdgcn_mfma_f32_16x16x16bf16_1k)
__device__ __forceinline__ f32x4 mfma16(s16x4 a, s16x4 b, f32x4 c) {
  return __builtin_amdgcn_mfma_f32_16x16x16bf16_1k(a, b, c, 0, 0, 0);
}
#else
__device__ __forceinline__ f32x4 mfma16(s16x4 a, s16x4 b, f32x4 c) {
  asm("v_mfma_f32_16x16x16_bf16 %0, %1, %2, %0" : "+v"(c) : "v"(a), "v"(b));
  return c;
}
#endif

__global__ void prep_weights(const float* __restrict__ wqkv,
                             const float* __restrict__ wproj,
                             __bf16* __restrict__ wbf) {
  int i = blockIdx.x * 256 + threadIdx.x;          // 65536 total
  float v = (i < 49152) ? wqkv[i] : wproj[i - 49152];
  if (i < 16384) v *= SCALE * LOG2E;               // fold softmax scale + log2e into Wq
  wbf[i] = (__bf16)v;
}

__global__ __launch_bounds__(128, 2)
void winattn_main(const float* __restrict__ x,
                  const __bf16* __restrict__ wqkv,   // [384][128] bf16 (Q rows pre-scaled)
                  const __bf16* __restrict__ wproj,  // [128][128] bf16
                  const float* __restrict__ bproj,
                  float* __restrict__ out) {
  __shared__ __align__(16) char smem[32768];

  const int tid  = threadIdx.x;
  const int lane = tid & 63;
  const int wv   = tid >> 6;       // 0,1: wave handles heads {2wv, 2wv+1}
  const int l15  = lane & 15;
  const int l4   = lane >> 4;

  // XCD-aware swizzle: XCD k owns batch k.
  const int bid = blockIdx.x;
  const int win = ((bid & 7) << 10) | (bid >> 3);
  const int b   = win >> 10;
  const int wy  = (win >> 5) & 31;
  const int wx  = win & 31;
  const int gy0 = wy * 8, gx0 = wx * 8;

  // ---------------- Phase A: load window -> Xt[tok][c] bf16 (swz &15) ----------------
  #pragma unroll
  for (int it = 0; it < 8; ++it) {
    int idx   = tid + it * 128;        // 1024 tasks: (cpair 64) x (ty 8) x (tx4 2)
    int cpair = idx >> 4;
    int r     = idx & 15;
    int ty    = r >> 1, tx4 = r & 1;
    const float* px = x + (((size_t)(b * 128 + 2 * cpair) * HH + gy0 + ty) * WWID + gx0 + tx4 * 4);
    float4 v0 = *(const float4*)px;
    float4 v1 = *(const float4*)(px + (size_t)HH * WWID);
    float a0[4] = {v0.x, v0.y, v0.z, v0.w};
    float a1[4] = {v1.x, v1.y, v1.z, v1.w};
    #pragma unroll
    for (int i = 0; i < 4; ++i) {
      int tok = ty * 8 + tx4 * 4 + i;
      bf16x2 w2 = {(__bf16)a0[i], (__bf16)a1[i]};
      int byte = (tok * 256 + cpair * 4) ^ ((tok & 15) << 4);
      *(bf16x2*)(smem + byte) = w2;
    }
  }
  __syncthreads();

  // Xt fragment; A- and B-operand lane mappings are identical.
  #define XT_AFRAG(mt, kt) \
    (*(const bf16x8*)(smem + ((((mt) * 16 + l15) * 256 + ((kt) * 32 + l4 * 8) * 2) ^ \
                              ((((mt) * 16 + l15) & 15) << 4))))
  #define OT_AFRAG(mt, kt) \
    (*(const bf16x8*)(smem + OT_BASE + ((((mt) * 16 + l15) * 256 + ((kt) * 32 + l4 * 8) * 2) ^ \
                              ((((mt) * 16 + l15) & 15) << 4))))

  // ================ per-head chain (2 heads, sequential, no sync) ================
  #pragma unroll 1
  for (int hl = 0; hl < 2; ++hl) {
    const int hh = wv * 2 + hl;       // head 0..3

    // ---- B1: Q & K fused, SWAPPED (lane=tok, regs=d) ----
    s16x4 qb[2][4], kb[2][4];
    {
      f32x4 accQ[2][4] = {}, accK[2][4] = {};
      #pragma unroll
      for (int kt = 0; kt < 4; ++kt) {
        bf16x8 xf[4];
        #pragma unroll
        for (int mt = 0; mt < 4; ++mt) xf[mt] = XT_AFRAG(mt, kt);
        #pragma unroll
        for (int nt2 = 0; nt2 < 2; ++nt2) {
          bf16x8 wq = *(const bf16x8*)(wqkv + (size_t)(hh * 32 + nt2 * 16 + l15) * 128 + kt * 32 + l4 * 8);
          bf16x8 wk = *(const bf16x8*)(wqkv + (size_t)(128 + hh * 32 + nt2 * 16 + l15) * 128 + kt * 32 + l4 * 8);
          __builtin_amdgcn_s_setprio(1);
          #pragma unroll
          for (int mt = 0; mt < 4; ++mt) {
            accQ[nt2][mt] = __builtin_amdgcn_mfma_f32_16x16x32_bf16(wq, xf[mt], accQ[nt2][mt], 0, 0, 0);
            accK[nt2][mt] = __builtin_amdgcn_mfma_f32_16x16x32_bf16(wk, xf[mt], accK[nt2][mt], 0, 0, 0);
          }
          __builtin_amdgcn_s_setprio(0);
        }
      }
      #pragma unroll
      for (int nt2 = 0; nt2 < 2; ++nt2)
        #pragma unroll
        for (int mt = 0; mt < 4; ++mt) {
          qb[nt2][mt] = pack4(accQ[nt2][mt]);
          kb[nt2][mt] = pack4(accK[nt2][mt]);
        }
    }

    // ---- C1: S^T + softmax -> packed P ----
    s16x4 ap[4][4];   // [q-tile t][key-tile m]; lane=q, regs=key
    #pragma unroll
    for (int t = 0; t < 4; ++t) {
      f32x4 st[4];
      __builtin_amdgcn_s_setprio(1);
      #pragma unroll
      for (int m = 0; m < 4; ++m) {
        f32x4 z = {0.f, 0.f, 0.f, 0.f};
        st[m] = mfma16(kb[0][m], qb[0][t], z);
        st[m] = mfma16(kb[1][m], qb[1][t], st[m]);
      }
      __builtin_amdgcn_s_setprio(0);
      float mx = st[0][0];
      #pragma unroll
      for (int m = 0; m < 4; ++m)
        #pragma unroll
        for (int r = 0; r < 4; ++r) mx = fmaxf(mx, st[m][r]);
      mx = fmaxf(mx, __shfl_xor(mx, 16));
      mx = fmaxf(mx, __shfl_xor(mx, 32));
      float p[4][4];
      float sm = 0.f;
      #pragma unroll
      for (int m = 0; m < 4; ++m)
        #pragma unroll
        for (int r = 0; r < 4; ++r) {
          p[m][r] = __builtin_amdgcn_exp2f(st[m][r] - mx);
          sm += p[m][r];
        }
      sm += __shfl_xor(sm, 16);
      sm += __shfl_xor(sm, 32);
      float inv = __builtin_amdgcn_rcpf(sm);
      #pragma unroll
      for (int m = 0; m < 4; ++m) {
        f32x4 pn = {p[m][0] * inv, p[m][1] * inv, p[m][2] * inv, p[m][3] * inv};
        ap[t][m] = pack4(pn);
      }
    }

    // ---- V pass (non-swapped: lane=d, regs=tok) ----
    s16x4 vb[2][4];
    {
      f32x4 acc[2][4] = {};
      #pragma unroll
      for (int kt = 0; kt < 4; ++kt) {
        bf16x8 xf[4];
        #pragma unroll
        for (int mt = 0; mt < 4; ++mt) xf[mt] = XT_AFRAG(mt, kt);
        #pragma unroll
        for (int nt2 = 0; nt2 < 2; ++nt2) {
          bf16x8 w = *(const bf16x8*)(wqkv + (size_t)(256 + hh * 32 + nt2 * 16 + l15) * 128 + kt * 32 + l4 * 8);
          __builtin_amdgcn_s_setprio(1);
          #pragma unroll
          for (int mt = 0; mt < 4; ++mt)
            acc[nt2][mt] = __builtin_amdgcn_mfma_f32_16x16x32_bf16(xf[mt], w, acc[nt2][mt], 0, 0, 0);
          __builtin_amdgcn_s_setprio(0);
        }
      }
      #pragma unroll
      for (int nt2 = 0; nt2 < 2; ++nt2)
        #pragma unroll
        for (int mt = 0; mt < 4; ++mt) vb[nt2][mt] = pack4(acc[nt2][mt]);
    }

    // ---- C2: PV transposed (lane=tok, regs=d) + packed Ot stores ----
    #pragma unroll
    for (int t = 0; t < 4; ++t) {
      f32x4 o0 = {0.f, 0.f, 0.f, 0.f}, o1 = {0.f, 0.f, 0.f, 0.f};
      __builtin_amdgcn_s_setprio(1);
      #pragma unroll
      for (int m = 0; m < 4; ++m) {
        o0 = mfma16(vb[0][m], ap[t][m], o0);   // D(lane=q/tok, regs=d)
        o1 = mfma16(vb[1][m], ap[t][m], o1);
      }
      __builtin_amdgcn_s_setprio(0);
      int tok = t * 16 + l15;
      int sw  = (tok & 15) << 4;
      s16x4 p0 = pack4(o0), p1 = pack4(o1);
      int c0 = hh * 32 + l4 * 4;              // 4 consecutive d per reg-group
      *(s16x4*)(smem + OT_BASE + ((tok * 256 + c0 * 2) ^ sw))          = p0;
      *(s16x4*)(smem + OT_BASE + ((tok * 256 + (c0 + 16) * 2) ^ sw))   = p1;
    }
  }
  __syncthreads();   // Ot complete (both waves, all 4 heads)

  // ---------------- Phase D: proj GEMM (wave owns 64 output channels) ----------------
  f32x4 pacc[4][4] = {};  // [o-tile i][tok-tile mt]
  #pragma unroll
  for (int kt = 0; kt < 4; ++kt) {
    bf16x8 of[4];
    #pragma unroll
    for (int mt = 0; mt < 4; ++mt) of[mt] = OT_AFRAG(mt, kt);
    #pragma unroll
    for (int i = 0; i < 4; ++i) {
      bf16x8 wp = *(const bf16x8*)(wproj + (size_t)(wv * 64 + i * 16 + l15) * 128 + kt * 32 + l4 * 8);
      __builtin_amdgcn_s_setprio(1);
      #pragma unroll
      for (int mt = 0; mt < 4; ++mt)
        pacc[i][mt] = __builtin_amdgcn_mfma_f32_16x16x32_bf16(of[mt], wp, pacc[i][mt], 0, 0, 0);
      __builtin_amdgcn_s_setprio(0);
    }
  }

  // ---------------- Phase E: direct float4 writeout + bias ----------------
  #pragma unroll
  for (int i = 0; i < 4; ++i) {
    int o = wv * 64 + i * 16 + l15;
    float bias = bproj[o];
    float* obase = out + (size_t)(b * 128 + o) * ((size_t)HH * WWID) + gy0 * WWID + gx0;
    #pragma unroll
    for (int mt = 0; mt < 4; ++mt) {
      int tok0 = mt * 16 + l4 * 4;            // 4 consecutive toks within one y-row
      int ty = tok0 >> 3, tx0 = tok0 & 7;
      float4 f = {pacc[i][mt][0] + bias, pacc[i][mt][1] + bias,
                  pacc[i][mt][2] + bias, pacc[i][mt][3] + bias};
      *(float4*)(obase + ty * WWID + tx0) = f;
    }
  }
}

extern "C" void kernel_launch(void* const* d_in, const int* in_sizes, int n_in,
                              void* d_out, int out_size, void* d_ws, size_t ws_size,
                              hipStream_t stream) {
  const float* x     = (const float*)d_in[0];
  const float* wqkv  = (const float*)d_in[1];
  const float* wproj = (const float*)d_in[2];
  const float* bproj = (const float*)d_in[3];
  float* out = (float*)d_out;

  __bf16* wbf = (__bf16*)d_ws;   // 65536 bf16 = 128 KiB scratch
  prep_weights<<<256, 256, 0, stream>>>(wqkv, wproj, wbf);
  winattn_main<<<8192, 128, 0, stream>>>(x, wbf, wbf + 49152, bproj, out);
}